// Round 6
// baseline (43.304 us; speedup 1.0000x reference)
//
#include <hip/hip_runtime.h>
#include <math.h>

#define NB 64
#define NS 4096
#define SEGS 8                  // segments (blocks) per batch
#define TPB 512                 // threads per block, 1 step per thread
#define STEPS (NS / SEGS)       // 512
#define NWAVES (TPB / 64)       // 8
#define NBLK (NB * SEGS)        // 512 blocks (== TPB, needed for final reduce)

// fallback (single-phase) params
#define FB_T 512
#define FB_CHUNK (NS / FB_T)
#define FB_W (FB_T / 64)

struct SE3 {
  float r[9];
  float t[3];
};

__device__ __forceinline__ void se3_id(SE3 &x) {
#pragma unroll
  for (int i = 0; i < 9; ++i) x.r[i] = 0.f;
  x.r[0] = x.r[4] = x.r[8] = 1.f;
  x.t[0] = x.t[1] = x.t[2] = 0.f;
}

__device__ __forceinline__ SE3 se3_mul(const SE3 &a, const SE3 &b) {
  SE3 c;
#pragma unroll
  for (int i = 0; i < 3; ++i) {
#pragma unroll
    for (int j = 0; j < 3; ++j) {
      c.r[i * 3 + j] = fmaf(a.r[i * 3 + 0], b.r[0 * 3 + j],
                       fmaf(a.r[i * 3 + 1], b.r[1 * 3 + j],
                            a.r[i * 3 + 2] * b.r[2 * 3 + j]));
    }
    c.t[i] = fmaf(a.r[i * 3 + 0], b.t[0],
             fmaf(a.r[i * 3 + 1], b.t[1],
             fmaf(a.r[i * 3 + 2], b.t[2], a.t[i])));
  }
  return c;
}

// fast acos: Abramowitz-Stegun 4.4.45 style, |err| <= 6.7e-5 rad
__device__ __forceinline__ float fast_acosf(float x) {
  const float ax = fabsf(x);
  float p = fmaf(ax, -0.0187293f, 0.0742610f);
  p = fmaf(p, ax, -0.2121144f);
  p = fmaf(p, ax, 1.5707288f);
  const float r = sqrtf(fmaxf(1.f - ax, 0.f)) * p;
  return (x >= 0.f) ? r : (3.14159274f - r);
}

__device__ __forceinline__ SE3 build_pose(float a, float b, float c,
                                          float tx, float ty, float tz) {
  float sa, ca, sb, cb, sc, cc;
  __sincosf(a, &sa, &ca);
  __sincosf(b, &sb, &cb);
  __sincosf(c, &sc, &cc);
  SE3 p;
  p.r[0] = cc * cb;
  p.r[1] = cc * sb * sa - sc * ca;
  p.r[2] = cc * sb * ca + sc * sa;
  p.r[3] = sc * cb;
  p.r[4] = sc * sb * sa + cc * ca;
  p.r[5] = sc * sb * ca - cc * sa;
  p.r[6] = -sb;
  p.r[7] = cb * sa;
  p.r[8] = cb * ca;
  p.t[0] = tx;
  p.t[1] = ty;
  p.t[2] = tz;
  return p;
}

__device__ __forceinline__ SE3 se3_shfl_up(const SE3 &x, int delta) {
  SE3 y;
#pragma unroll
  for (int i = 0; i < 9; ++i) y.r[i] = __shfl_up(x.r[i], delta, 64);
#pragma unroll
  for (int i = 0; i < 3; ++i) y.t[i] = __shfl_up(x.t[i], delta, 64);
  return y;
}

__device__ __forceinline__ float geo_angle(const SE3 &A, const SE3 &B) {
  float dot = 0.f;
#pragma unroll
  for (int k = 0; k < 9; ++k) dot = fmaf(A.r[k], B.r[k], dot);
  float cosv = 0.5f * (dot - 1.f);
  cosv = fminf(fmaxf(cosv, -1.f + 1e-6f), 1.f - 1e-6f);
  return fast_acosf(cosv);
}

// block-local scan shared by k1/k2: returns this thread's block-local
// inclusive prefix (Le, Lg) of the shifted pose sequence.
__device__ __forceinline__ void block_scan(const SE3 &Pe, const SE3 &Pg, int s,
                                           int lane, int wave, SE3 &Le,
                                           SE3 &Lg) {
  SE3 Ie = Pe, Ig = Pg;
  if (s == 0) {  // shifted[0] = identity
    se3_id(Ie);
    se3_id(Ig);
  }

#pragma unroll
  for (int o = 1; o < 64; o <<= 1) {
    SE3 pe = se3_shfl_up(Ie, o);
    SE3 pg = se3_shfl_up(Ig, o);
    if (lane >= o) {
      Ie = se3_mul(pe, Ie);
      Ig = se3_mul(pg, Ig);
    }
  }

  __shared__ float aggE[NWAVES][12];
  __shared__ float aggG[NWAVES][12];
  if (lane == 63) {
#pragma unroll
    for (int k = 0; k < 9; ++k) {
      aggE[wave][k] = Ie.r[k];
      aggG[wave][k] = Ig.r[k];
    }
#pragma unroll
    for (int k = 0; k < 3; ++k) {
      aggE[wave][9 + k] = Ie.t[k];
      aggG[wave][9 + k] = Ig.t[k];
    }
  }
  __syncthreads();

  SE3 We, Wg;
  se3_id(We);
  se3_id(Wg);
  for (int w = 0; w < wave; ++w) {
    SE3 ae, ag;
#pragma unroll
    for (int k = 0; k < 9; ++k) {
      ae.r[k] = aggE[w][k];
      ag.r[k] = aggG[w][k];
    }
#pragma unroll
    for (int k = 0; k < 3; ++k) {
      ae.t[k] = aggE[w][9 + k];
      ag.t[k] = aggG[w][9 + k];
    }
    We = se3_mul(We, ae);
    Wg = se3_mul(Wg, ag);
  }

  Le = se3_mul(We, Ie);
  Lg = se3_mul(Wg, Ig);
}

// reduce 3 floats across the block; result valid in thread 0
__device__ __forceinline__ void block_reduce3(float &v0, float &v1, float &v2,
                                              int lane, int wave) {
#pragma unroll
  for (int o = 32; o > 0; o >>= 1) {
    v0 += __shfl_xor(v0, o, 64);
    v1 += __shfl_xor(v1, o, 64);
    v2 += __shfl_xor(v2, o, 64);
  }
  __shared__ float red[NWAVES][3];
  if (lane == 0) {
    red[wave][0] = v0;
    red[wave][1] = v1;
    red[wave][2] = v2;
  }
  __syncthreads();
  if (wave == 0 && lane == 0) {
    float a = 0.f, b = 0.f, c = 0.f;
#pragma unroll
    for (int w = 0; w < NWAVES; ++w) {
      a += red[w][0];
      b += red[w][1];
      c += red[w][2];
    }
    v0 = a;
    v1 = b;
    v2 = c;
  }
  __syncthreads();  // red[] reused by callers / later reductions
}

// ws layout (bytes):
//   [0,4)        int counter
//   [256, ...)   float aggs [NBLK][24]   (est 12 + gt 12)
//   then         float part1[NBLK][3]    (odom partials)
//   then         float part2[NBLK][3]    (traj partials)

__global__ __launch_bounds__(TPB) void k1_scan(
    const float *__restrict__ y_hat, const float *__restrict__ gt_pos,
    const float *__restrict__ gt_ori, float *__restrict__ aggs,
    float *__restrict__ part1, int *__restrict__ counter) {
  const int blk = blockIdx.x;
  const int b = blk >> 3;
  const int seg = blk & (SEGS - 1);
  const int tid = threadIdx.x;
  const int lane = tid & 63;
  const int wave = tid >> 6;
  const int s = seg * STEPS + tid;

  if (blk == 0 && tid == 0) *counter = 0;  // reset for k2's last-block logic

  const float *y6 = y_hat + ((size_t)b * NS + s) * 6;
  const float *g3 = gt_pos + ((size_t)b * NS + s) * 3;
  const float *o3 = gt_ori + ((size_t)b * NS + s) * 3;

  const float px = y6[3], py = y6[4], pz = y6[5];
  const float gx = g3[0], gy = g3[1], gz = g3[2];
  SE3 Pe = build_pose(y6[0], y6[1], y6[2], px, py, pz);
  SE3 Pg = build_pose(o3[0], o3[1], o3[2], gx, gy, gz);

  const float dx = px - gx, dy = py - gy, dz = pz - gz;
  float s_sq = dx * dx + dy * dy + dz * dz;
  float s_abs = fabsf(dx) + fabsf(dy) + fabsf(dz);
  float s_rot = geo_angle(Pe, Pg);

  SE3 Le, Lg;
  block_scan(Pe, Pg, s, lane, wave, Le, Lg);

  // last thread's inclusive prefix = segment aggregate
  if (tid == TPB - 1) {
    float *ag = aggs + (size_t)blk * 24;
#pragma unroll
    for (int k = 0; k < 9; ++k) {
      ag[k] = Le.r[k];
      ag[12 + k] = Lg.r[k];
    }
#pragma unroll
    for (int k = 0; k < 3; ++k) {
      ag[9 + k] = Le.t[k];
      ag[21 + k] = Lg.t[k];
    }
  }

  block_reduce3(s_sq, s_abs, s_rot, lane, wave);
  if (tid == 0) {
    float *dst = part1 + (size_t)blk * 3;
    dst[0] = s_sq;
    dst[1] = s_abs;
    dst[2] = s_rot;
  }
}

__global__ __launch_bounds__(TPB) void k2_traj(
    const float *__restrict__ y_hat, const float *__restrict__ gt_pos,
    const float *__restrict__ gt_ori, const float *__restrict__ aggs,
    const float *__restrict__ part1, float *__restrict__ part2,
    int *__restrict__ counter, float *__restrict__ out) {
  const int blk = blockIdx.x;
  const int b = blk >> 3;
  const int seg = blk & (SEGS - 1);
  const int tid = threadIdx.x;
  const int lane = tid & 63;
  const int wave = tid >> 6;
  const int s = seg * STEPS + tid;

  const float *y6 = y_hat + ((size_t)b * NS + s) * 6;
  const float *g3 = gt_pos + ((size_t)b * NS + s) * 3;
  const float *o3 = gt_ori + ((size_t)b * NS + s) * 3;

  SE3 Pe = build_pose(y6[0], y6[1], y6[2], y6[3], y6[4], y6[5]);
  SE3 Pg = build_pose(o3[0], o3[1], o3[2], g3[0], g3[1], g3[2]);

  SE3 Le, Lg;
  block_scan(Pe, Pg, s, lane, wave, Le, Lg);

  // exclusive prefix over preceding segment aggregates (from k1)
  SE3 Ee, Eg;
  se3_id(Ee);
  se3_id(Eg);
  const float *abase = aggs + (size_t)(b * SEGS) * 24;
  for (int w = 0; w < seg; ++w) {
    const float *ag = abase + (size_t)w * 24;
    SE3 ae, agm;
#pragma unroll
    for (int k = 0; k < 9; ++k) {
      ae.r[k] = ag[k];
      agm.r[k] = ag[12 + k];
    }
#pragma unroll
    for (int k = 0; k < 3; ++k) {
      ae.t[k] = ag[9 + k];
      agm.t[k] = ag[21 + k];
    }
    Ee = se3_mul(Ee, ae);
    Eg = se3_mul(Eg, agm);
  }

  SE3 Te = se3_mul(Ee, Le);
  SE3 Tg = se3_mul(Eg, Lg);

  const float dx = Te.t[0] - Tg.t[0];
  const float dy = Te.t[1] - Tg.t[1];
  const float dz = Te.t[2] - Tg.t[2];
  float s_sq = dx * dx + dy * dy + dz * dz;
  float s_abs = fabsf(dx) + fabsf(dy) + fabsf(dz);
  float s_rot = geo_angle(Te, Tg);

  block_reduce3(s_sq, s_abs, s_rot, lane, wave);

  // publish partials (device-scope atomics: safe across XCD L2s), then
  // the last-arriving block reduces everything and writes the output.
  __shared__ int sh_last;
  if (tid == 0) {
    atomicExch(&part2[(size_t)blk * 3 + 0], s_sq);
    atomicExch(&part2[(size_t)blk * 3 + 1], s_abs);
    atomicExch(&part2[(size_t)blk * 3 + 2], s_rot);
    __threadfence();
    const int old = atomicAdd(counter, 1);
    sh_last = (old == NBLK - 1) ? 1 : 0;
  }
  __syncthreads();

  if (sh_last) {
    __threadfence();
    // NBLK == TPB: thread tid owns block tid's partials
    float v[6];
#pragma unroll
    for (int k = 0; k < 3; ++k) {
      v[k] = part1[(size_t)tid * 3 + k];                    // k1: dispatch-ordered
      v[3 + k] = atomicAdd(&part2[(size_t)tid * 3 + k], 0.f);  // device-scope read
    }
#pragma unroll
    for (int o = 32; o > 0; o >>= 1) {
#pragma unroll
      for (int k = 0; k < 6; ++k) v[k] += __shfl_xor(v[k], o, 64);
    }
    __shared__ float red6[NWAVES][6];
    if (lane == 0) {
#pragma unroll
      for (int k = 0; k < 6; ++k) red6[wave][k] = v[k];
    }
    __syncthreads();
    if (tid == 0) {
      double a[6];
#pragma unroll
      for (int k = 0; k < 6; ++k) {
        double t = 0.0;
#pragma unroll
        for (int w = 0; w < NWAVES; ++w) t += (double)red6[w][k];
        a[k] = t;
      }
      const double n3 = (double)NB * (double)NS * 3.0;
      const double n1 = (double)NB * (double)NS;
      const double odom = a[2] / n1 + (a[0] / n3 + a[1] / n3);
      const double traj = a[5] / n1 + (a[3] / n3 + a[4] / n3);
      out[0] = (float)(0.5 * odom + 0.5 * traj);
    }
  }
}

// ---------------- fallback single-phase path (atomics, tiny ws) ------------
__global__ __launch_bounds__(FB_T) void traj_loss_main(
    const float *__restrict__ y_hat, const float *__restrict__ gt_pos,
    const float *__restrict__ gt_ori, double *__restrict__ acc) {
  const int b = blockIdx.x;
  const int tid = threadIdx.x;
  const int lane = tid & 63;
  const int wave = tid >> 6;
  const int s0 = tid * FB_CHUNK;

  const float *yb = y_hat + (size_t)b * NS * 6;
  const float *gp = gt_pos + (size_t)b * NS * 3;
  const float *go = gt_ori + (size_t)b * NS * 3;

  float s_sq_pos = 0.f, s_abs_pos = 0.f, s_rot_odom = 0.f;

  SE3 Le, Lg;
  se3_id(Le);
  se3_id(Lg);

  for (int i = 0; i < FB_CHUNK; ++i) {
    const int s = s0 + i;
    const float *y6 = yb + (size_t)s * 6;
    const float *g3 = gp + (size_t)s * 3;
    const float *o3 = go + (size_t)s * 3;
    const float px = y6[3], py = y6[4], pz = y6[5];
    const float gx = g3[0], gy = g3[1], gz = g3[2];

    SE3 Pe = build_pose(y6[0], y6[1], y6[2], px, py, pz);
    SE3 Pg = build_pose(o3[0], o3[1], o3[2], gx, gy, gz);

    const float dx = px - gx, dy = py - gy, dz = pz - gz;
    s_sq_pos += dx * dx + dy * dy + dz * dz;
    s_abs_pos += fabsf(dx) + fabsf(dy) + fabsf(dz);
    s_rot_odom += geo_angle(Pe, Pg);

    if (s != 0) {
      Le = se3_mul(Le, Pe);
      Lg = se3_mul(Lg, Pg);
    }
  }

  SE3 Ie = Le, Ig = Lg;
#pragma unroll
  for (int o = 1; o < 64; o <<= 1) {
    SE3 pe = se3_shfl_up(Ie, o);
    SE3 pg = se3_shfl_up(Ig, o);
    if (lane >= o) {
      Ie = se3_mul(pe, Ie);
      Ig = se3_mul(pg, Ig);
    }
  }

  __shared__ float aggE[FB_W][12];
  __shared__ float aggG[FB_W][12];
  if (lane == 63) {
#pragma unroll
    for (int k = 0; k < 9; ++k) {
      aggE[wave][k] = Ie.r[k];
      aggG[wave][k] = Ig.r[k];
    }
#pragma unroll
    for (int k = 0; k < 3; ++k) {
      aggE[wave][9 + k] = Ie.t[k];
      aggG[wave][9 + k] = Ig.t[k];
    }
  }
  __syncthreads();

  SE3 Te, Tg;
  se3_id(Te);
  se3_id(Tg);
  for (int w = 0; w < wave; ++w) {
    SE3 ae, ag;
#pragma unroll
    for (int k = 0; k < 9; ++k) {
      ae.r[k] = aggE[w][k];
      ag.r[k] = aggG[w][k];
    }
#pragma unroll
    for (int k = 0; k < 3; ++k) {
      ae.t[k] = aggE[w][9 + k];
      ag.t[k] = aggG[w][9 + k];
    }
    Te = se3_mul(Te, ae);
    Tg = se3_mul(Tg, ag);
  }

  SE3 Ee = se3_shfl_up(Ie, 1);
  SE3 Eg = se3_shfl_up(Ig, 1);
  if (lane == 0) {
    se3_id(Ee);
    se3_id(Eg);
  }
  Te = se3_mul(Te, Ee);
  Tg = se3_mul(Tg, Eg);

  float s_sq_tr = 0.f, s_abs_tr = 0.f, s_rot_tr = 0.f;
  for (int i = 0; i < FB_CHUNK; ++i) {
    const int s = s0 + i;
    const float *y6 = yb + (size_t)s * 6;
    const float *g3 = gp + (size_t)s * 3;
    const float *o3 = go + (size_t)s * 3;
    if (s != 0) {
      SE3 Pe = build_pose(y6[0], y6[1], y6[2], y6[3], y6[4], y6[5]);
      SE3 Pg = build_pose(o3[0], o3[1], o3[2], g3[0], g3[1], g3[2]);
      Te = se3_mul(Te, Pe);
      Tg = se3_mul(Tg, Pg);
    }
    const float dx = Te.t[0] - Tg.t[0];
    const float dy = Te.t[1] - Tg.t[1];
    const float dz = Te.t[2] - Tg.t[2];
    s_sq_tr += dx * dx + dy * dy + dz * dz;
    s_abs_tr += fabsf(dx) + fabsf(dy) + fabsf(dz);
    s_rot_tr += geo_angle(Te, Tg);
  }

#pragma unroll
  for (int o = 32; o > 0; o >>= 1) {
    s_sq_pos += __shfl_xor(s_sq_pos, o, 64);
    s_abs_pos += __shfl_xor(s_abs_pos, o, 64);
    s_rot_odom += __shfl_xor(s_rot_odom, o, 64);
    s_sq_tr += __shfl_xor(s_sq_tr, o, 64);
    s_abs_tr += __shfl_xor(s_abs_tr, o, 64);
    s_rot_tr += __shfl_xor(s_rot_tr, o, 64);
  }
  if (lane == 0) {
    atomicAdd(&acc[0], (double)s_sq_pos);
    atomicAdd(&acc[1], (double)s_abs_pos);
    atomicAdd(&acc[2], (double)s_rot_odom);
    atomicAdd(&acc[3], (double)s_sq_tr);
    atomicAdd(&acc[4], (double)s_abs_tr);
    atomicAdd(&acc[5], (double)s_rot_tr);
  }
}

__global__ void init_acc(double *acc) {
  const int i = threadIdx.x;
  if (i < 6) acc[i] = 0.0;
}

__global__ void finalize_acc(const double *__restrict__ acc,
                             float *__restrict__ out) {
  const double n3 = (double)NB * (double)NS * 3.0;
  const double n1 = (double)NB * (double)NS;
  const double odom = acc[2] / n1 + (acc[0] / n3 + acc[1] / n3);
  const double traj = acc[5] / n1 + (acc[3] / n3 + acc[4] / n3);
  out[0] = (float)(0.5 * odom + 0.5 * traj);
}

extern "C" void kernel_launch(void *const *d_in, const int *in_sizes, int n_in,
                              void *d_out, int out_size, void *d_ws,
                              size_t ws_size, hipStream_t stream) {
  const float *y_hat = (const float *)d_in[0];
  const float *gt_pos = (const float *)d_in[1];
  const float *gt_ori = (const float *)d_in[2];

  int *counter = (int *)d_ws;
  float *aggs = (float *)((char *)d_ws + 256);
  float *part1 = aggs + (size_t)NBLK * 24;
  float *part2 = part1 + (size_t)NBLK * 3;
  const size_t need = 256 + (size_t)NBLK * (24 + 3 + 3) * sizeof(float);

  if (ws_size >= need) {
    k1_scan<<<NBLK, TPB, 0, stream>>>(y_hat, gt_pos, gt_ori, aggs, part1,
                                      counter);
    k2_traj<<<NBLK, TPB, 0, stream>>>(y_hat, gt_pos, gt_ori, aggs, part1,
                                      part2, counter, (float *)d_out);
  } else {
    double *acc = (double *)d_ws;
    init_acc<<<1, 64, 0, stream>>>(acc);
    traj_loss_main<<<NB, FB_T, 0, stream>>>(y_hat, gt_pos, gt_ori, acc);
    finalize_acc<<<1, 1, 0, stream>>>(acc, (float *)d_out);
  }
}

// Round 7
// 30.991 us; speedup vs baseline: 1.3973x; 1.3973x over previous
//
#include <hip/hip_runtime.h>
#include <math.h>

#define NB 64
#define NS 4096
#define SEGS 8                   // segments (blocks) per batch
#define TPB 256                  // threads per block
#define CHUNK 2                  // elements per thread
#define STEPS (NS / SEGS)        // 512 elements per segment
#define NWAVES (TPB / 64)        // 4
#define NBLK (NB * SEGS)         // 512 blocks
#define FTPB 512                 // finalize threads (== NBLK)

// fallback (single-phase) params
#define FB_T 512
#define FB_CHUNK (NS / FB_T)
#define FB_W (FB_T / 64)

struct SE3 {
  float r[9];
  float t[3];
};

__device__ __forceinline__ void se3_id(SE3 &x) {
#pragma unroll
  for (int i = 0; i < 9; ++i) x.r[i] = 0.f;
  x.r[0] = x.r[4] = x.r[8] = 1.f;
  x.t[0] = x.t[1] = x.t[2] = 0.f;
}

__device__ __forceinline__ SE3 se3_mul(const SE3 &a, const SE3 &b) {
  SE3 c;
#pragma unroll
  for (int i = 0; i < 3; ++i) {
#pragma unroll
    for (int j = 0; j < 3; ++j) {
      c.r[i * 3 + j] = fmaf(a.r[i * 3 + 0], b.r[0 * 3 + j],
                       fmaf(a.r[i * 3 + 1], b.r[1 * 3 + j],
                            a.r[i * 3 + 2] * b.r[2 * 3 + j]));
    }
    c.t[i] = fmaf(a.r[i * 3 + 0], b.t[0],
             fmaf(a.r[i * 3 + 1], b.t[1],
             fmaf(a.r[i * 3 + 2], b.t[2], a.t[i])));
  }
  return c;
}

// fast acos: Abramowitz-Stegun 4.4.45 style, |err| <= 6.7e-5 rad
__device__ __forceinline__ float fast_acosf(float x) {
  const float ax = fabsf(x);
  float p = fmaf(ax, -0.0187293f, 0.0742610f);
  p = fmaf(p, ax, -0.2121144f);
  p = fmaf(p, ax, 1.5707288f);
  const float r = sqrtf(fmaxf(1.f - ax, 0.f)) * p;
  return (x >= 0.f) ? r : (3.14159274f - r);
}

__device__ __forceinline__ SE3 build_pose(float a, float b, float c,
                                          float tx, float ty, float tz) {
  float sa, ca, sb, cb, sc, cc;
  __sincosf(a, &sa, &ca);
  __sincosf(b, &sb, &cb);
  __sincosf(c, &sc, &cc);
  SE3 p;
  p.r[0] = cc * cb;
  p.r[1] = cc * sb * sa - sc * ca;
  p.r[2] = cc * sb * ca + sc * sa;
  p.r[3] = sc * cb;
  p.r[4] = sc * sb * sa + cc * ca;
  p.r[5] = sc * sb * ca - cc * sa;
  p.r[6] = -sb;
  p.r[7] = cb * sa;
  p.r[8] = cb * ca;
  p.t[0] = tx;
  p.t[1] = ty;
  p.t[2] = tz;
  return p;
}

__device__ __forceinline__ SE3 se3_shfl_up(const SE3 &x, int delta) {
  SE3 y;
#pragma unroll
  for (int i = 0; i < 9; ++i) y.r[i] = __shfl_up(x.r[i], delta, 64);
#pragma unroll
  for (int i = 0; i < 3; ++i) y.t[i] = __shfl_up(x.t[i], delta, 64);
  return y;
}

__device__ __forceinline__ float geo_angle(const SE3 &A, const SE3 &B) {
  float dot = 0.f;
#pragma unroll
  for (int k = 0; k < 9; ++k) dot = fmaf(A.r[k], B.r[k], dot);
  float cosv = 0.5f * (dot - 1.f);
  cosv = fminf(fmaxf(cosv, -1.f + 1e-6f), 1.f - 1e-6f);
  return fast_acosf(cosv);
}

// pack/unpack SE3 <-> 3x float4  ({r0..r3},{r4..r7},{r8,t0,t1,t2})
__device__ __forceinline__ void se3_store(float4 *base, size_t stride, int s,
                                          const SE3 &x) {
  base[0 * stride + s] = make_float4(x.r[0], x.r[1], x.r[2], x.r[3]);
  base[1 * stride + s] = make_float4(x.r[4], x.r[5], x.r[6], x.r[7]);
  base[2 * stride + s] = make_float4(x.r[8], x.t[0], x.t[1], x.t[2]);
}

__device__ __forceinline__ SE3 se3_load(const float4 *base, size_t stride,
                                        int s) {
  const float4 a = base[0 * stride + s];
  const float4 b = base[1 * stride + s];
  const float4 c = base[2 * stride + s];
  SE3 x;
  x.r[0] = a.x; x.r[1] = a.y; x.r[2] = a.z; x.r[3] = a.w;
  x.r[4] = b.x; x.r[5] = b.y; x.r[6] = b.z; x.r[7] = b.w;
  x.r[8] = c.x; x.t[0] = c.y; x.t[1] = c.z; x.t[2] = c.w;
  return x;
}

// block-reduce 3 floats; thread 0 writes dst[0..2]
__device__ __forceinline__ void block_reduce3_store(float v0, float v1,
                                                    float v2,
                                                    float *__restrict__ dst,
                                                    int lane, int wave,
                                                    int tid) {
#pragma unroll
  for (int o = 32; o > 0; o >>= 1) {
    v0 += __shfl_xor(v0, o, 64);
    v1 += __shfl_xor(v1, o, 64);
    v2 += __shfl_xor(v2, o, 64);
  }
  __shared__ float red[NWAVES][3];
  if (lane == 0) {
    red[wave][0] = v0;
    red[wave][1] = v1;
    red[wave][2] = v2;
  }
  __syncthreads();
  if (tid == 0) {
    float a = 0.f, b = 0.f, c = 0.f;
#pragma unroll
    for (int w = 0; w < NWAVES; ++w) {
      a += red[w][0];
      b += red[w][1];
      c += red[w][2];
    }
    dst[0] = a;
    dst[1] = b;
    dst[2] = c;
  }
}

// ws layout (floats):
//   wsl   : NB * 24 * NS   (per-step block-local prefixes, float4-packed)
//   part1 : NBLK * 3
//   part2 : NBLK * 3

__global__ __launch_bounds__(TPB) void k1_scan(
    const float *__restrict__ y_hat, const float *__restrict__ gt_pos,
    const float *__restrict__ gt_ori, float *__restrict__ wsl,
    float *__restrict__ part1) {
  const int blk = blockIdx.x;
  const int b = blk >> 3;
  const int seg = blk & (SEGS - 1);
  const int tid = threadIdx.x;
  const int lane = tid & 63;
  const int wave = tid >> 6;
  const int s0 = seg * STEPS + tid * CHUNK;  // this thread: s0, s0+1

  float s_sq = 0.f, s_abs = 0.f, s_rot = 0.f;

  // ---- build both poses, accumulate odom terms, shift s==0 to identity
  SE3 P1e, P1g, P2e, P2g;
  {
    const float *y6 = y_hat + ((size_t)b * NS + s0) * 6;
    const float *g3 = gt_pos + ((size_t)b * NS + s0) * 3;
    const float *o3 = gt_ori + ((size_t)b * NS + s0) * 3;
    const float px = y6[3], py = y6[4], pz = y6[5];
    const float gx = g3[0], gy = g3[1], gz = g3[2];
    P1e = build_pose(y6[0], y6[1], y6[2], px, py, pz);
    P1g = build_pose(o3[0], o3[1], o3[2], gx, gy, gz);
    const float dx = px - gx, dy = py - gy, dz = pz - gz;
    s_sq += dx * dx + dy * dy + dz * dz;
    s_abs += fabsf(dx) + fabsf(dy) + fabsf(dz);
    s_rot += geo_angle(P1e, P1g);
    if (s0 == 0) {  // shifted[0] = identity
      se3_id(P1e);
      se3_id(P1g);
    }
  }
  {
    const int s1 = s0 + 1;
    const float *y6 = y_hat + ((size_t)b * NS + s1) * 6;
    const float *g3 = gt_pos + ((size_t)b * NS + s1) * 3;
    const float *o3 = gt_ori + ((size_t)b * NS + s1) * 3;
    const float px = y6[3], py = y6[4], pz = y6[5];
    const float gx = g3[0], gy = g3[1], gz = g3[2];
    P2e = build_pose(y6[0], y6[1], y6[2], px, py, pz);
    P2g = build_pose(o3[0], o3[1], o3[2], gx, gy, gz);
    const float dx = px - gx, dy = py - gy, dz = pz - gz;
    s_sq += dx * dx + dy * dy + dz * dz;
    s_abs += fabsf(dx) + fabsf(dy) + fabsf(dz);
    s_rot += geo_angle(P2e, P2g);
  }

  // ---- thread aggregate = P1 * P2, then wave Kogge-Stone over aggregates
  SE3 Ie = se3_mul(P1e, P2e);
  SE3 Ig = se3_mul(P1g, P2g);

#pragma unroll
  for (int o = 1; o < 64; o <<= 1) {
    SE3 pe = se3_shfl_up(Ie, o);
    SE3 pg = se3_shfl_up(Ig, o);
    if (lane >= o) {
      Ie = se3_mul(pe, Ie);
      Ig = se3_mul(pg, Ig);
    }
  }

  // lane-exclusive prefix of thread aggregates
  SE3 Ee = se3_shfl_up(Ie, 1);
  SE3 Eg = se3_shfl_up(Ig, 1);
  if (lane == 0) {
    se3_id(Ee);
    se3_id(Eg);
  }

  // ---- cross-wave prefix
  __shared__ float aggE[NWAVES][12];
  __shared__ float aggG[NWAVES][12];
  if (lane == 63) {
#pragma unroll
    for (int k = 0; k < 9; ++k) {
      aggE[wave][k] = Ie.r[k];
      aggG[wave][k] = Ig.r[k];
    }
#pragma unroll
    for (int k = 0; k < 3; ++k) {
      aggE[wave][9 + k] = Ie.t[k];
      aggG[wave][9 + k] = Ig.t[k];
    }
  }
  __syncthreads();

  SE3 We, Wg;
  se3_id(We);
  se3_id(Wg);
  for (int w = 0; w < wave; ++w) {
    SE3 ae, ag;
#pragma unroll
    for (int k = 0; k < 9; ++k) {
      ae.r[k] = aggE[w][k];
      ag.r[k] = aggG[w][k];
    }
#pragma unroll
    for (int k = 0; k < 3; ++k) {
      ae.t[k] = aggE[w][9 + k];
      ag.t[k] = aggG[w][9 + k];
    }
    We = se3_mul(We, ae);
    Wg = se3_mul(Wg, ag);
  }

  // thread's block-exclusive base, then walk the 2 held poses
  SE3 Be = se3_mul(We, Ee);
  SE3 Bg = se3_mul(Wg, Eg);

  SE3 L1e = se3_mul(Be, P1e);
  SE3 L1g = se3_mul(Bg, P1g);
  SE3 L2e = se3_mul(L1e, P2e);
  SE3 L2g = se3_mul(L1g, P2g);

  // ---- store per-step prefixes (float4-packed SoA)
  float4 *wb4 = (float4 *)(wsl + (size_t)b * 24 * NS);
  float4 *wbE = wb4;
  float4 *wbG = wb4 + (size_t)3 * NS;
  se3_store(wbE, NS, s0, L1e);
  se3_store(wbE, NS, s0 + 1, L2e);
  se3_store(wbG, NS, s0, L1g);
  se3_store(wbG, NS, s0 + 1, L2g);

  block_reduce3_store(s_sq, s_abs, s_rot, part1 + (size_t)blk * 3, lane, wave,
                      tid);
}

__global__ __launch_bounds__(TPB) void k3_traj(const float *__restrict__ wsl,
                                               float *__restrict__ part2) {
  const int blk = blockIdx.x;
  const int b = blk >> 3;
  const int seg = blk & (SEGS - 1);
  const int tid = threadIdx.x;
  const int lane = tid & 63;
  const int wave = tid >> 6;
  const int s0 = seg * STEPS + tid * CHUNK;

  const float4 *wb4 = (const float4 *)(wsl + (size_t)b * 24 * NS);
  const float4 *wbE = wb4;
  const float4 *wbG = wb4 + (size_t)3 * NS;

  // segment-exclusive prefix (uniform per block; L1-broadcast loads)
  SE3 Ee, Eg;
  se3_id(Ee);
  se3_id(Eg);
  for (int w = 0; w < seg; ++w) {
    const int sl = w * STEPS + (STEPS - 1);
    SE3 ae = se3_load(wbE, NS, sl);
    SE3 ag = se3_load(wbG, NS, sl);
    Ee = se3_mul(Ee, ae);
    Eg = se3_mul(Eg, ag);
  }

  float s_sq = 0.f, s_abs = 0.f, s_rot = 0.f;
#pragma unroll
  for (int i = 0; i < CHUNK; ++i) {
    SE3 Le = se3_load(wbE, NS, s0 + i);
    SE3 Lg = se3_load(wbG, NS, s0 + i);
    SE3 Te = se3_mul(Ee, Le);
    SE3 Tg = se3_mul(Eg, Lg);
    const float dx = Te.t[0] - Tg.t[0];
    const float dy = Te.t[1] - Tg.t[1];
    const float dz = Te.t[2] - Tg.t[2];
    s_sq += dx * dx + dy * dy + dz * dz;
    s_abs += fabsf(dx) + fabsf(dy) + fabsf(dz);
    s_rot += geo_angle(Te, Tg);
  }

  block_reduce3_store(s_sq, s_abs, s_rot, part2 + (size_t)blk * 3, lane, wave,
                      tid);
}

__global__ __launch_bounds__(FTPB) void finalize_parts(
    const float *__restrict__ part1, const float *__restrict__ part2,
    float *__restrict__ out) {
  const int tid = threadIdx.x;
  const int lane = tid & 63;
  const int wave = tid >> 6;

  float v[6];
#pragma unroll
  for (int k = 0; k < 3; ++k) {
    v[k] = part1[(size_t)tid * 3 + k];
    v[3 + k] = part2[(size_t)tid * 3 + k];
  }
#pragma unroll
  for (int o = 32; o > 0; o >>= 1) {
#pragma unroll
    for (int k = 0; k < 6; ++k) v[k] += __shfl_xor(v[k], o, 64);
  }
  __shared__ float red[FTPB / 64][6];
  if (lane == 0) {
#pragma unroll
    for (int k = 0; k < 6; ++k) red[wave][k] = v[k];
  }
  __syncthreads();
  if (tid == 0) {
    double a[6];
#pragma unroll
    for (int k = 0; k < 6; ++k) {
      double t = 0.0;
#pragma unroll
      for (int w = 0; w < FTPB / 64; ++w) t += (double)red[w][k];
      a[k] = t;
    }
    const double n3 = (double)NB * (double)NS * 3.0;
    const double n1 = (double)NB * (double)NS;
    const double odom = a[2] / n1 + (a[0] / n3 + a[1] / n3);
    const double traj = a[5] / n1 + (a[3] / n3 + a[4] / n3);
    out[0] = (float)(0.5 * odom + 0.5 * traj);
  }
}

// ---------------- fallback single-phase path (atomics, tiny ws) ------------
__global__ __launch_bounds__(FB_T) void traj_loss_main(
    const float *__restrict__ y_hat, const float *__restrict__ gt_pos,
    const float *__restrict__ gt_ori, double *__restrict__ acc) {
  const int b = blockIdx.x;
  const int tid = threadIdx.x;
  const int lane = tid & 63;
  const int wave = tid >> 6;
  const int s0 = tid * FB_CHUNK;

  const float *yb = y_hat + (size_t)b * NS * 6;
  const float *gp = gt_pos + (size_t)b * NS * 3;
  const float *go = gt_ori + (size_t)b * NS * 3;

  float s_sq_pos = 0.f, s_abs_pos = 0.f, s_rot_odom = 0.f;

  SE3 Le, Lg;
  se3_id(Le);
  se3_id(Lg);

  for (int i = 0; i < FB_CHUNK; ++i) {
    const int s = s0 + i;
    const float *y6 = yb + (size_t)s * 6;
    const float *g3 = gp + (size_t)s * 3;
    const float *o3 = go + (size_t)s * 3;
    const float px = y6[3], py = y6[4], pz = y6[5];
    const float gx = g3[0], gy = g3[1], gz = g3[2];

    SE3 Pe = build_pose(y6[0], y6[1], y6[2], px, py, pz);
    SE3 Pg = build_pose(o3[0], o3[1], o3[2], gx, gy, gz);

    const float dx = px - gx, dy = py - gy, dz = pz - gz;
    s_sq_pos += dx * dx + dy * dy + dz * dz;
    s_abs_pos += fabsf(dx) + fabsf(dy) + fabsf(dz);
    s_rot_odom += geo_angle(Pe, Pg);

    if (s != 0) {
      Le = se3_mul(Le, Pe);
      Lg = se3_mul(Lg, Pg);
    }
  }

  SE3 Ie = Le, Ig = Lg;
#pragma unroll
  for (int o = 1; o < 64; o <<= 1) {
    SE3 pe = se3_shfl_up(Ie, o);
    SE3 pg = se3_shfl_up(Ig, o);
    if (lane >= o) {
      Ie = se3_mul(pe, Ie);
      Ig = se3_mul(pg, Ig);
    }
  }

  __shared__ float aggE[FB_W][12];
  __shared__ float aggG[FB_W][12];
  if (lane == 63) {
#pragma unroll
    for (int k = 0; k < 9; ++k) {
      aggE[wave][k] = Ie.r[k];
      aggG[wave][k] = Ig.r[k];
    }
#pragma unroll
    for (int k = 0; k < 3; ++k) {
      aggE[wave][9 + k] = Ie.t[k];
      aggG[wave][9 + k] = Ig.t[k];
    }
  }
  __syncthreads();

  SE3 Te, Tg;
  se3_id(Te);
  se3_id(Tg);
  for (int w = 0; w < wave; ++w) {
    SE3 ae, ag;
#pragma unroll
    for (int k = 0; k < 9; ++k) {
      ae.r[k] = aggE[w][k];
      ag.r[k] = aggG[w][k];
    }
#pragma unroll
    for (int k = 0; k < 3; ++k) {
      ae.t[k] = aggE[w][9 + k];
      ag.t[k] = aggG[w][9 + k];
    }
    Te = se3_mul(Te, ae);
    Tg = se3_mul(Tg, ag);
  }

  SE3 Ee = se3_shfl_up(Ie, 1);
  SE3 Eg = se3_shfl_up(Ig, 1);
  if (lane == 0) {
    se3_id(Ee);
    se3_id(Eg);
  }
  Te = se3_mul(Te, Ee);
  Tg = se3_mul(Tg, Eg);

  float s_sq_tr = 0.f, s_abs_tr = 0.f, s_rot_tr = 0.f;
  for (int i = 0; i < FB_CHUNK; ++i) {
    const int s = s0 + i;
    const float *y6 = yb + (size_t)s * 6;
    const float *g3 = gp + (size_t)s * 3;
    const float *o3 = go + (size_t)s * 3;
    if (s != 0) {
      SE3 Pe = build_pose(y6[0], y6[1], y6[2], y6[3], y6[4], y6[5]);
      SE3 Pg = build_pose(o3[0], o3[1], o3[2], g3[0], g3[1], g3[2]);
      Te = se3_mul(Te, Pe);
      Tg = se3_mul(Tg, Pg);
    }
    const float dx = Te.t[0] - Tg.t[0];
    const float dy = Te.t[1] - Tg.t[1];
    const float dz = Te.t[2] - Tg.t[2];
    s_sq_tr += dx * dx + dy * dy + dz * dz;
    s_abs_tr += fabsf(dx) + fabsf(dy) + fabsf(dz);
    s_rot_tr += geo_angle(Te, Tg);
  }

#pragma unroll
  for (int o = 32; o > 0; o >>= 1) {
    s_sq_pos += __shfl_xor(s_sq_pos, o, 64);
    s_abs_pos += __shfl_xor(s_abs_pos, o, 64);
    s_rot_odom += __shfl_xor(s_rot_odom, o, 64);
    s_sq_tr += __shfl_xor(s_sq_tr, o, 64);
    s_abs_tr += __shfl_xor(s_abs_tr, o, 64);
    s_rot_tr += __shfl_xor(s_rot_tr, o, 64);
  }
  if (lane == 0) {
    atomicAdd(&acc[0], (double)s_sq_pos);
    atomicAdd(&acc[1], (double)s_abs_pos);
    atomicAdd(&acc[2], (double)s_rot_odom);
    atomicAdd(&acc[3], (double)s_sq_tr);
    atomicAdd(&acc[4], (double)s_abs_tr);
    atomicAdd(&acc[5], (double)s_rot_tr);
  }
}

__global__ void init_acc(double *acc) {
  const int i = threadIdx.x;
  if (i < 6) acc[i] = 0.0;
}

__global__ void finalize_acc(const double *__restrict__ acc,
                             float *__restrict__ out) {
  const double n3 = (double)NB * (double)NS * 3.0;
  const double n1 = (double)NB * (double)NS;
  const double odom = acc[2] / n1 + (acc[0] / n3 + acc[1] / n3);
  const double traj = acc[5] / n1 + (acc[3] / n3 + acc[4] / n3);
  out[0] = (float)(0.5 * odom + 0.5 * traj);
}

extern "C" void kernel_launch(void *const *d_in, const int *in_sizes, int n_in,
                              void *d_out, int out_size, void *d_ws,
                              size_t ws_size, hipStream_t stream) {
  const float *y_hat = (const float *)d_in[0];
  const float *gt_pos = (const float *)d_in[1];
  const float *gt_ori = (const float *)d_in[2];

  float *wsl = (float *)d_ws;
  const size_t wsl_elems = (size_t)NB * 24 * NS;
  float *part1 = wsl + wsl_elems;
  float *part2 = part1 + (size_t)NBLK * 3;
  const size_t need = (wsl_elems + (size_t)NBLK * 6) * sizeof(float);

  if (ws_size >= need) {
    k1_scan<<<NBLK, TPB, 0, stream>>>(y_hat, gt_pos, gt_ori, wsl, part1);
    k3_traj<<<NBLK, TPB, 0, stream>>>(wsl, part2);
    finalize_parts<<<1, FTPB, 0, stream>>>(part1, part2, (float *)d_out);
  } else {
    double *acc = (double *)d_ws;
    init_acc<<<1, 64, 0, stream>>>(acc);
    traj_loss_main<<<NB, FB_T, 0, stream>>>(y_hat, gt_pos, gt_ori, acc);
    finalize_acc<<<1, 1, 0, stream>>>(acc, (float *)d_out);
  }
}